// Round 1
// baseline (705.281 us; speedup 1.0000x reference)
//
#include <hip/hip_runtime.h>

// GlobalGOCorOpt fused kernel for MI355X (gfx950).
// B=2, NF=4096, C=256, H=W=64, HW=4096, NUM_ITER=2, NUM_BINS=10, BIN_DISP=0.5
//
// Structure: one block = (batch b, tile of 32 filters). The whole 2-iteration
// optimizer runs inside the block (per-filter independence). GEMMs use
// f16 MFMA 16x16x32 with fp32 accumulation; masters kept in fp32.

#define NFILT 4096
#define CDIM  256
#define HWDIM 4096

typedef _Float16 f16;
typedef _Float16 f16x8 __attribute__((ext_vector_type(8)));
typedef float f32x4 __attribute__((ext_vector_type(4)));

// XOR swizzle inside a [32][256] f16 LDS tile: spreads the 16 row-reads of an
// MFMA A-fragment (row stride 512B) across banks. Bijective per row.
__device__ __forceinline__ int swz(int f, int j) {
  return f * 256 + (((j >> 3) ^ (f & 7)) << 3) + (j & 7);
}

// ---------- kernel 0: the three 127x127 maps (label, v_plus, sigmoid(mask)) ----------
__global__ __launch_bounds__(256) void k_maps(
    const float* __restrict__ wl, const float* __restrict__ wsp,
    const float* __restrict__ wmk,
    float* __restrict__ label_t, float* __restrict__ vplus_t,
    float* __restrict__ wm_t)
{
  int i = blockIdx.x * 256 + threadIdx.x;
  if (i >= 127 * 127) return;
  int yy = i / 127, xx = i - yy * 127;
  float dy = (float)yy - 63.f, dx = (float)xx - 63.f;
  float d2 = 2.f * sqrtf(dy * dy + dx * dx);   // dist / BIN_DISP
  float l = 0.f, v = 0.f, m = 0.f;
#pragma unroll
  for (int k = 0; k < 9; ++k) {                // "rest" bins: relu(1-|d2-k|)
    float t = fmaxf(1.f - fabsf(d2 - (float)k), 0.f);
    l += wl[k] * t; v += wsp[k] * t; m += wmk[k] * t;
  }
  float t9 = fminf(fmaxf(d2 - 8.f, 0.f), 1.f); // last bin: clip(1+(d2-9),0,1)
  l += wl[9] * t9; v += wsp[9] * t9; m += wmk[9] * t9;
  label_t[i] = l;
  vplus_t[i] = v;
  wm_t[i] = 1.f / (1.f + expf(-m));            // sigmoid applied here
}

// ---------- kernel 1: feat f32 -> f16 [b][c][yx] and transposed f16 [b][yx][c] ----------
__global__ __launch_bounds__(256) void k_convert(
    const float* __restrict__ feat, f16* __restrict__ featc,
    f16* __restrict__ featT)
{
  __shared__ float tbuf[64][65];
  int bid = blockIdx.x;                        // 512 blocks = 2b x 4cb x 64yb
  int b = bid >> 8, cb = (bid >> 6) & 3, yb = bid & 63;
  int ty = threadIdx.x & 63, tc = threadIdx.x >> 6;
  const float* src = feat + ((size_t)b * CDIM + cb * 64) * HWDIM + yb * 64;
#pragma unroll
  for (int s = 0; s < 16; ++s) {
    int c = s * 4 + tc;
    float v = src[(size_t)c * HWDIM + ty];
    tbuf[c][ty] = v;
    featc[((size_t)b * CDIM + cb * 64 + c) * HWDIM + yb * 64 + ty] = (f16)v;
  }
  __syncthreads();
#pragma unroll
  for (int s = 0; s < 16; ++s) {
    int y = s * 4 + tc;
    featT[((size_t)b * HWDIM + yb * 64 + y) * CDIM + cb * 64 + ty] = (f16)tbuf[ty][y];
  }
}

// ---------- kernel 2: fused 2-iteration GOCor optimizer ----------
__global__ __launch_bounds__(256) void k_gocor(
    const float* __restrict__ filt_g,          // [B][NF][C] f32
    const f16*  __restrict__ featc,            // [B][C][HW] f16
    const f16*  __restrict__ featT,            // [B][HW][C] f16
    const float* __restrict__ label_t,
    const float* __restrict__ vplus_t,
    const float* __restrict__ wm_t,
    const float* __restrict__ lsl,
    const float* __restrict__ freg,
    unsigned long long* __restrict__ sgn_ws,   // [gridDim][2048] sign ballots
    float* __restrict__ out)                   // [B][NF][C] f32
{
  // 64 KB static LDS, carved by hand.
  __shared__ __align__(16) unsigned char smem[65536];
  float* filt32 = (float*)smem;                // [32][256] f32 master filter
  f16*   filt16 = (f16*)(smem + 32768);        // [32][256] f16 (swizzled): filt, then fgrad, then new filt
  f16*   mresS  = (f16*)(smem + 49152);        // [32][256] f16 (swizzled) mres chunk
  float* redbuf = (float*)(smem + 49152);      // alias into mres region (bar-separated)
  float* anumS  = redbuf + 128;                // [32]
  float* alphaS = redbuf + 160;                // [32]

  const int tid = threadIdx.x;
  const int w   = tid >> 6;                    // wave 0..3
  const int lane = tid & 63;
  const int llo = lane & 15, lhi = lane >> 4;

  // XCD-aware decode: XCDs 0-3 -> batch 0, XCDs 4-7 -> batch 1 (L2 locality).
  const int bid  = blockIdx.x;
  const int xcd  = bid & 7, slot = bid >> 3;   // slot 0..31
  const int b    = (xcd >= 4) ? 1 : 0;
  const int tile = (xcd & 3) * 32 + slot;      // 0..127
  const int f0   = tile * 32;
  const int py   = f0 >> 6, pxb = f0 & 63;

  const float sl = expf(lsl[0]);
  const float fr = freg[0];
  const float rw = fmaxf(fr * fr, 1e-10f);     // MIN_FILTER_REG^2

  const float* filtg = filt_g + ((size_t)b * NFILT + f0) * CDIM;
  const f16* fT = featT + (size_t)b * HWDIM * CDIM;
  const f16* fC = featc + (size_t)b * CDIM * HWDIM;
  unsigned long long* sgnB = sgn_ws + (size_t)bid * 2048;

  // init filter tile: thread==c layout
#pragma unroll
  for (int f = 0; f < 32; ++f) {
    float v = filtg[f * CDIM + tid];
    filt32[f * 256 + tid] = v;
    filt16[swz(f, tid)] = (f16)v;
  }
  __syncthreads();

  for (int it = 0; it < 2; ++it) {
    // fgrad_loss accumulator: persistent MFMA fragments, wave w owns c in [w*64, w*64+64)
    f32x4 facc[2][4];
#pragma unroll
    for (int mi = 0; mi < 2; ++mi)
#pragma unroll
      for (int ni = 0; ni < 4; ++ni)
        facc[mi][ni] = (f32x4){0.f, 0.f, 0.f, 0.f};

    // ================= pass 1: scores -> mres -> fgrad_loss =================
    for (int ch = 0; ch < 16; ++ch) {          // 16 chunks of 256 yx (4 y-rows)
      // ---- GEMM1: scores[f][yx] = sum_c filt[f][c] * feat[c][yx]
      // wave w handles yx slice ch*256 + w*64 .. +64 (exactly y-row ch*4+w)
      f32x4 sc[2][4];
#pragma unroll
      for (int mi = 0; mi < 2; ++mi)
#pragma unroll
        for (int ni = 0; ni < 4; ++ni)
          sc[mi][ni] = (f32x4){0.f, 0.f, 0.f, 0.f};
      {
        const f16* Bp = fT + ((size_t)(ch * 256 + w * 64)) * CDIM;
#pragma unroll
        for (int k = 0; k < 8; ++k) {
          const int ko = k * 32 + lhi * 8;
          f16x8 a0 = *(const f16x8*)&filt16[swz(llo, ko)];
          f16x8 a1 = *(const f16x8*)&filt16[swz(16 + llo, ko)];
#pragma unroll
          for (int ni = 0; ni < 4; ++ni) {
            f16x8 bv = *(const f16x8*)&Bp[(ni * 16 + llo) * CDIM + ko];
            sc[0][ni] = __builtin_amdgcn_mfma_f32_16x16x32_f16(a0, bv, sc[0][ni], 0, 0, 0);
            sc[1][ni] = __builtin_amdgcn_mfma_f32_16x16x32_f16(a1, bv, sc[1][ni], 0, 0, 0);
          }
        }
      }
      // ---- epilogue: mres = dact*(act - vp*label), sign ballots
      {
        const int iy = 63 - py + ch * 4 + w;   // uniform per wave
        const int tb = iy * 127 + 63 - pxb;
#pragma unroll
        for (int mi = 0; mi < 2; ++mi)
#pragma unroll
          for (int ni = 0; ni < 4; ++ni)
#pragma unroll
            for (int r = 0; r < 4; ++r) {
              const int fl = mi * 16 + lhi * 4 + r;  // D row
              const int x  = ni * 16 + llo;          // D col
              const int t  = tb - fl + x;
              const float s  = sc[mi][ni][r];
              const float lab = label_t[t];
              const float vp  = vplus_t[t];
              const float aa  = wm_t[t];
              const float sg0 = (s > 0.f) ? 1.f : ((s < 0.f) ? -1.f : 0.f);
              const float act = vp * 0.5f * ((1.f - aa) * fabsf(s) + (1.f + aa) * s);
              const float dct = vp * 0.5f * ((1.f - aa) * sg0 + (1.f + aa));
              const float mr  = dct * (act - vp * lab);
              mresS[swz(fl, w * 64 + x)] = (f16)mr;
              unsigned long long bm = __ballot(s > 0.f);
              if (lane == 0) sgnB[((ch * 4 + w) * 2 + mi) * 16 + ni * 4 + r] = bm;
            }
      }
      __syncthreads();
      // ---- GEMM2: facc[f][c] += sum_yx mres[f][yx] * feat[c][yx]
      {
#pragma unroll
        for (int k = 0; k < 8; ++k) {
          const int ko = k * 32 + lhi * 8;
          f16x8 a0 = *(const f16x8*)&mresS[swz(llo, ko)];
          f16x8 a1 = *(const f16x8*)&mresS[swz(16 + llo, ko)];
#pragma unroll
          for (int ni = 0; ni < 4; ++ni) {
            const f16* bp2 = fC + ((size_t)(w * 64 + ni * 16 + llo)) * HWDIM + ch * 256 + ko;
            f16x8 bv = *(const f16x8*)bp2;
            facc[0][ni] = __builtin_amdgcn_mfma_f32_16x16x32_f16(a0, bv, facc[0][ni], 0, 0, 0);
            facc[1][ni] = __builtin_amdgcn_mfma_f32_16x16x32_f16(a1, bv, facc[1][ni], 0, 0, 0);
          }
        }
      }
      __syncthreads();
    }

    // ================= fgrad = rw*filt + loss; alpha_num =================
    float nump[8];
#pragma unroll
    for (int i = 0; i < 8; ++i) nump[i] = 0.f;
#pragma unroll
    for (int mi = 0; mi < 2; ++mi)
#pragma unroll
      for (int ni = 0; ni < 4; ++ni)
#pragma unroll
        for (int r = 0; r < 4; ++r) {
          const int fl = mi * 16 + lhi * 4 + r;
          const int c  = w * 64 + ni * 16 + llo;
          float fg = rw * filt32[fl * 256 + c] + facc[mi][ni][r];
          facc[mi][ni][r] = fg;                 // facc now holds fgrad (fp32)
          filt16[swz(fl, c)] = (f16)fg;         // A-operand for GEMM3
          nump[mi * 4 + r] += fg * fg;
        }
#pragma unroll
    for (int i = 0; i < 8; ++i) {
      float v = nump[i];
      v += __shfl_xor(v, 1); v += __shfl_xor(v, 2);
      v += __shfl_xor(v, 4); v += __shfl_xor(v, 8);
      nump[i] = v;
    }
    __syncthreads();                            // mres region free -> redbuf alias OK
    if (llo == 0) {
#pragma unroll
      for (int i = 0; i < 8; ++i) {
        const int fl = (i >> 2) * 16 + lhi * 4 + (i & 3);
        redbuf[w * 32 + fl] = nump[i];
      }
    }
    __syncthreads();
    if (tid < 32)
      anumS[tid] = redbuf[tid] + redbuf[32 + tid] + redbuf[64 + tid] + redbuf[96 + tid];

    // ================= pass 2: sg -> den_res -> alpha_den =================
    float dacc[8];
#pragma unroll
    for (int i = 0; i < 8; ++i) dacc[i] = 0.f;
    for (int ch = 0; ch < 16; ++ch) {
      f32x4 sgf[2][4];
#pragma unroll
      for (int mi = 0; mi < 2; ++mi)
#pragma unroll
        for (int ni = 0; ni < 4; ++ni)
          sgf[mi][ni] = (f32x4){0.f, 0.f, 0.f, 0.f};
      {
        const f16* Bp = fT + ((size_t)(ch * 256 + w * 64)) * CDIM;
#pragma unroll
        for (int k = 0; k < 8; ++k) {
          const int ko = k * 32 + lhi * 8;
          f16x8 a0 = *(const f16x8*)&filt16[swz(llo, ko)];       // = fgrad
          f16x8 a1 = *(const f16x8*)&filt16[swz(16 + llo, ko)];
#pragma unroll
          for (int ni = 0; ni < 4; ++ni) {
            f16x8 bv = *(const f16x8*)&Bp[(ni * 16 + llo) * CDIM + ko];
            sgf[0][ni] = __builtin_amdgcn_mfma_f32_16x16x32_f16(a0, bv, sgf[0][ni], 0, 0, 0);
            sgf[1][ni] = __builtin_amdgcn_mfma_f32_16x16x32_f16(a1, bv, sgf[1][ni], 0, 0, 0);
          }
        }
      }
      {
        const int iy = 63 - py + ch * 4 + w;
        const int tb = iy * 127 + 63 - pxb;
#pragma unroll
        for (int mi = 0; mi < 2; ++mi)
#pragma unroll
          for (int ni = 0; ni < 4; ++ni)
#pragma unroll
            for (int r = 0; r < 4; ++r) {
              const int fl = mi * 16 + lhi * 4 + r;
              const int x  = ni * 16 + llo;
              const int t  = tb - fl + x;
              const float vp = vplus_t[t];
              const float aa = wm_t[t];
              unsigned long long bm = sgnB[((ch * 4 + w) * 2 + mi) * 16 + ni * 4 + r];
              const float sg0 = ((bm >> lane) & 1ULL) ? 1.f : -1.f;
              const float dct = vp * 0.5f * ((1.f - aa) * sg0 + (1.f + aa));
              const float dr  = dct * sgf[mi][ni][r];
              dacc[mi * 4 + r] += dr * dr;
            }
      }
    }
#pragma unroll
    for (int i = 0; i < 8; ++i) {
      float v = dacc[i];
      v += __shfl_xor(v, 1); v += __shfl_xor(v, 2);
      v += __shfl_xor(v, 4); v += __shfl_xor(v, 8);
      dacc[i] = v;
    }
    __syncthreads();                            // all waves past GEMM3/anum reads
    if (llo == 0) {
#pragma unroll
      for (int i = 0; i < 8; ++i) {
        const int fl = (i >> 2) * 16 + lhi * 4 + (i & 3);
        redbuf[w * 32 + fl] = dacc[i];
      }
    }
    __syncthreads();
    if (tid < 32) {
      float num = anumS[tid];
      float den = redbuf[tid] + redbuf[32 + tid] + redbuf[64 + tid] + redbuf[96 + tid];
      alphaS[tid] = num / fmaxf(den + rw * num, 1e-8f);  // STEPLEN_REG = 0
    }
    __syncthreads();
    // ================= update: filt -= sl*alpha*fgrad =================
#pragma unroll
    for (int mi = 0; mi < 2; ++mi)
#pragma unroll
      for (int ni = 0; ni < 4; ++ni)
#pragma unroll
        for (int r = 0; r < 4; ++r) {
          const int fl = mi * 16 + lhi * 4 + r;
          const int c  = w * 64 + ni * 16 + llo;
          const float al = alphaS[fl];
          const float nv = filt32[fl * 256 + c] - sl * al * facc[mi][ni][r];
          filt32[fl * 256 + c] = nv;
          filt16[swz(fl, c)] = (f16)nv;
        }
    __syncthreads();
  }

  float* og = out + ((size_t)b * NFILT + f0) * CDIM;
#pragma unroll
  for (int f = 0; f < 32; ++f) og[f * CDIM + tid] = filt32[f * 256 + tid];
}

extern "C" void kernel_launch(void* const* d_in, const int* in_sizes, int n_in,
                              void* d_out, int out_size, void* d_ws, size_t ws_size,
                              hipStream_t stream) {
  (void)in_sizes; (void)n_in; (void)out_size; (void)ws_size;
  const float* filt  = (const float*)d_in[0];   // filter_map [2][4096][256]
  const float* rfeat = (const float*)d_in[1];   // reference_feat [1][2][256][64][64]
  // d_in[2] query_feat: unused by the reference
  const float* wl  = (const float*)d_in[3];
  const float* wsp = (const float*)d_in[4];
  const float* wmk = (const float*)d_in[5];
  const float* lsl = (const float*)d_in[6];
  const float* fre = (const float*)d_in[7];

  char* ws = (char*)d_ws;
  float* label_t = (float*)(ws + 0);            //  64 KB region (16129 used)
  float* vplus_t = (float*)(ws + 65536);
  float* wm_t    = (float*)(ws + 131072);
  f16*   featc   = (f16*)(ws + 196608);         // 4 MB
  f16*   featT   = (f16*)(ws + 4390912);        // 4 MB
  unsigned long long* sgn = (unsigned long long*)(ws + 8585216);  // 4 MB
  float* out = (float*)d_out;

  k_maps<<<64, 256, 0, stream>>>(wl, wsp, wmk, label_t, vplus_t, wm_t);
  k_convert<<<512, 256, 0, stream>>>(rfeat, featc, featT);
  k_gocor<<<256, 256, 0, stream>>>(filt, featc, featT, label_t, vplus_t, wm_t,
                                   lsl, fre, sgn, out);
}

// Round 2
// 601.059 us; speedup vs baseline: 1.1734x; 1.1734x over previous
//
#include <hip/hip_runtime.h>

// GlobalGOCorOpt fused kernel for MI355X (gfx950) — round 2.
// B=2, NF=4096, C=256, H=W=64, HW=4096, NUM_ITER=2, NUM_BINS=10, BIN_DISP=0.5
// One block = (batch, 32-filter tile), 512 threads (8 waves), grid 256.
// f16 MFMA 16x16x32, fp32 accum; master filter lives in MFMA fragment regs.

#define NFILT 4096
#define CDIM  256
#define HWDIM 4096

typedef _Float16 f16;
typedef _Float16 f16x8 __attribute__((ext_vector_type(8)));
typedef float f32x4 __attribute__((ext_vector_type(4)));

// XOR swizzle within a row-major [*][ld] f16 LDS tile (ld multiple of 64):
// spreads 8 consecutive rows across 8 16-byte slots -> 2-way max on b128 reads.
__device__ __forceinline__ int swz(int f, int j, int ld) {
  return f * ld + (((j >> 3) ^ (f & 7)) << 3) + (j & 7);
}

// lgkm-only barrier: DS ops pinned, global loads may stay in flight across it.
#define LGKM_BARRIER() do {                         \
    __builtin_amdgcn_sched_barrier(0x7F);           \
    asm volatile("s_waitcnt lgkmcnt(0)");           \
    __builtin_amdgcn_s_barrier();                   \
    __builtin_amdgcn_sched_barrier(0x7F);           \
  } while (0)

// ---------- kernel 0: packed map table {vp*label, vp, sigmoid(mask), 0} ----------
__global__ __launch_bounds__(256) void k_maps(
    const float* __restrict__ wl, const float* __restrict__ wsp,
    const float* __restrict__ wmk, float4* __restrict__ tbl)
{
  int i = blockIdx.x * 256 + threadIdx.x;
  if (i >= 127 * 127) return;
  int yy = i / 127, xx = i - yy * 127;
  float dy = (float)yy - 63.f, dx = (float)xx - 63.f;
  float d2 = 2.f * sqrtf(dy * dy + dx * dx);   // dist / BIN_DISP
  float l = 0.f, v = 0.f, m = 0.f;
#pragma unroll
  for (int k = 0; k < 9; ++k) {
    float t = fmaxf(1.f - fabsf(d2 - (float)k), 0.f);
    l += wl[k] * t; v += wsp[k] * t; m += wmk[k] * t;
  }
  float t9 = fminf(fmaxf(d2 - 8.f, 0.f), 1.f);
  l += wl[9] * t9; v += wsp[9] * t9; m += wmk[9] * t9;
  tbl[i] = make_float4(v * l, v, 1.f / (1.f + expf(-m)), 0.f);
}

// ---------- kernel 1: feat f32 -> f16 [b][c][yx] and transposed [b][yx][c] ----------
__global__ __launch_bounds__(256) void k_convert(
    const float* __restrict__ feat, f16* __restrict__ featc,
    f16* __restrict__ featT)
{
  __shared__ float tbuf[64][65];
  int bid = blockIdx.x;                        // 512 blocks = 2b x 4cb x 64yb
  int b = bid >> 8, cb = (bid >> 6) & 3, yb = bid & 63;
  int ty = threadIdx.x & 63, tc = threadIdx.x >> 6;
  const float* src = feat + ((size_t)b * CDIM + cb * 64) * HWDIM + yb * 64;
#pragma unroll
  for (int s = 0; s < 16; ++s) {
    int c = s * 4 + tc;
    float v = src[(size_t)c * HWDIM + ty];
    tbuf[c][ty] = v;
    featc[((size_t)b * CDIM + cb * 64 + c) * HWDIM + yb * 64 + ty] = (f16)v;
  }
  __syncthreads();
#pragma unroll
  for (int s = 0; s < 16; ++s) {
    int y = s * 4 + tc;
    featT[((size_t)b * HWDIM + yb * 64 + y) * CDIM + cb * 64 + ty] = (f16)tbuf[ty][y];
  }
}

// ---------- kernel 2: fused 2-iteration GOCor optimizer ----------
__global__ __launch_bounds__(512, 2) void k_gocor(
    const float* __restrict__ filt_g,          // [B][NF][C] f32
    const f16*  __restrict__ featc,            // [B][C][HW] f16
    const f16*  __restrict__ featT,            // [B][HW][C] f16
    const float4* __restrict__ tbl,            // [127*127] {vp*lab, vp, wm, 0}
    const float* __restrict__ lsl,
    const float* __restrict__ freg,
    unsigned int* __restrict__ sgn_ws,         // [grid][8ch][8w][64lane] sign words
    float* __restrict__ out)                   // [B][NF][C] f32
{
  __shared__ __align__(16) unsigned char smem[50688];
  f16*   filt16 = (f16*)smem;                  // [32][256] f16 swz: filt / fgrad
  f16*   mresS  = (f16*)(smem + 16384);        // [32][512] f16 swz, chunk mres
  float* redbuf = (float*)(smem + 49152);      // [8][32]
  float* anumS  = redbuf + 256;                // [32]
  float* alphaS = anumS + 32;                  // [32]

  const int tid  = threadIdx.x;
  const int w    = tid >> 6;                   // wave 0..7
  const int lane = tid & 63;
  const int llo  = lane & 15, lhi = lane >> 4;

  // XCD-aware decode: XCDs 0-3 -> batch 0, XCDs 4-7 -> batch 1.
  const int bid  = blockIdx.x;
  const int xcd  = bid & 7, slot = bid >> 3;
  const int b    = (xcd >= 4) ? 1 : 0;
  const int tile = (xcd & 3) * 32 + slot;      // 0..127
  const int f0   = tile * 32;
  const int py   = f0 >> 6, pxb = f0 & 63;

  const float sl = expf(lsl[0]);
  const float fr = freg[0];
  const float rw = fmaxf(fr * fr, 1e-10f);     // MIN_FILTER_REG^2

  const f16* fT = featT + (size_t)b * HWDIM * CDIM;
  const f16* fC = featc + (size_t)b * CDIM * HWDIM;
  unsigned int* sgnB = sgn_ws + (size_t)bid * 4096;

  // Master filter in GEMM2-fragment registers: (fl, c) owner.
  // fl = mi*16 + lhi*4 + r ; c = w*32 + nj*16 + llo
  f32x4 fm[2][2];
  {
    const float* fg0 = filt_g + ((size_t)b * NFILT + f0) * CDIM;
#pragma unroll
    for (int mi = 0; mi < 2; ++mi)
#pragma unroll
      for (int nj = 0; nj < 2; ++nj)
#pragma unroll
        for (int r = 0; r < 4; ++r) {
          const int fl = mi * 16 + lhi * 4 + r;
          const int c  = w * 32 + nj * 16 + llo;
          float v = fg0[fl * CDIM + c];
          fm[mi][nj][r] = v;
          filt16[swz(fl, c, 256)] = (f16)v;
        }
  }
  __syncthreads();

  for (int it = 0; it < 2; ++it) {
    f32x4 facc[2][2];                          // fgrad_loss -> fgrad fragments
#pragma unroll
    for (int mi = 0; mi < 2; ++mi)
#pragma unroll
      for (int nj = 0; nj < 2; ++nj)
        facc[mi][nj] = (f32x4){0.f, 0.f, 0.f, 0.f};

    // ================= pass 1: scores -> mres -> fgrad_loss =================
    for (int ch = 0; ch < 8; ++ch) {           // 8 chunks of 512 yx (8 y-rows)
      // ---- GEMM1: scores[f][yx]; wave w owns y-row ch*8+w (64 x)
      f32x4 sc[2][4];
#pragma unroll
      for (int mi = 0; mi < 2; ++mi)
#pragma unroll
        for (int ni = 0; ni < 4; ++ni)
          sc[mi][ni] = (f32x4){0.f, 0.f, 0.f, 0.f};
      {
        const f16* Bp = fT + (size_t)(ch * 512 + w * 64) * CDIM;
#pragma unroll
        for (int k = 0; k < 8; ++k) {
          const int ko = k * 32 + lhi * 8;
          f16x8 a0 = *(const f16x8*)&filt16[swz(llo, ko, 256)];
          f16x8 a1 = *(const f16x8*)&filt16[swz(16 + llo, ko, 256)];
#pragma unroll
          for (int ni = 0; ni < 4; ++ni) {
            f16x8 bv = *(const f16x8*)&Bp[(ni * 16 + llo) * CDIM + ko];
            sc[0][ni] = __builtin_amdgcn_mfma_f32_16x16x32_f16(a0, bv, sc[0][ni], 0, 0, 0);
            sc[1][ni] = __builtin_amdgcn_mfma_f32_16x16x32_f16(a1, bv, sc[1][ni], 0, 0, 0);
          }
        }
      }
      // ---- epilogue: mres = dct*(act - vp*lab); pack sign bits
      {
        const int iy = 63 - py + ch * 8 + w;
        const int tb = iy * 127 + 63 - pxb;
        unsigned int sbits = 0u;
#pragma unroll
        for (int mi = 0; mi < 2; ++mi)
#pragma unroll
          for (int ni = 0; ni < 4; ++ni)
#pragma unroll
            for (int r = 0; r < 4; ++r) {
              const int fl = mi * 16 + lhi * 4 + r;
              const int x  = ni * 16 + llo;
              const float4 tv = tbl[tb - fl + x];
              const float s  = sc[mi][ni][r];
              const float q  = 0.5f * tv.y;           // 0.5*vp
              const float qa = q * tv.z;              // 0.5*vp*a
              const float h1 = q - qa, h2 = q + qa;
              const float sg0 = (s > 0.f) ? 1.f : ((s < 0.f) ? -1.f : 0.f);
              const float act = h1 * fabsf(s) + h2 * s;
              const float dct = h1 * sg0 + h2;
              const float mr  = dct * (act - tv.x);   // tv.x = vp*label
              mresS[swz(fl, w * 64 + x, 512)] = (f16)mr;
              sbits |= (s > 0.f ? 1u : 0u) << (mi * 16 + ni * 4 + r);
            }
        sgnB[(ch * 8 + w) * 64 + lane] = sbits;
      }
      LGKM_BARRIER();
      // ---- GEMM2: facc[f][c] += mres[f][yx] * feat[c][yx] over this chunk
      {
#pragma unroll
        for (int k = 0; k < 16; ++k) {
          const int ko = k * 32 + lhi * 8;
          f16x8 a0 = *(const f16x8*)&mresS[swz(llo, ko, 512)];
          f16x8 a1 = *(const f16x8*)&mresS[swz(16 + llo, ko, 512)];
#pragma unroll
          for (int nj = 0; nj < 2; ++nj) {
            const f16* bp = fC + (size_t)(w * 32 + nj * 16 + llo) * HWDIM + ch * 512 + ko;
            f16x8 bv = *(const f16x8*)bp;
            facc[0][nj] = __builtin_amdgcn_mfma_f32_16x16x32_f16(a0, bv, facc[0][nj], 0, 0, 0);
            facc[1][nj] = __builtin_amdgcn_mfma_f32_16x16x32_f16(a1, bv, facc[1][nj], 0, 0, 0);
          }
        }
      }
      LGKM_BARRIER();
    }

    // ================= fgrad = rw*filt + loss; alpha_num =================
    float nump[8];
#pragma unroll
    for (int i = 0; i < 8; ++i) nump[i] = 0.f;
#pragma unroll
    for (int mi = 0; mi < 2; ++mi)
#pragma unroll
      for (int nj = 0; nj < 2; ++nj)
#pragma unroll
        for (int r = 0; r < 4; ++r) {
          const int fl = mi * 16 + lhi * 4 + r;
          const int c  = w * 32 + nj * 16 + llo;
          float fg = rw * fm[mi][nj][r] + facc[mi][nj][r];
          facc[mi][nj][r] = fg;                 // facc now = fgrad (fp32)
          filt16[swz(fl, c, 256)] = (f16)fg;    // A-operand for GEMM3
          nump[mi * 4 + r] += fg * fg;
        }
#pragma unroll
    for (int i = 0; i < 8; ++i) {
      float v = nump[i];
      v += __shfl_xor(v, 1); v += __shfl_xor(v, 2);
      v += __shfl_xor(v, 4); v += __shfl_xor(v, 8);
      nump[i] = v;
    }
    __syncthreads();                            // full drain (also sgn stores)
    if (llo == 0) {
#pragma unroll
      for (int i = 0; i < 8; ++i) {
        const int fl = (i >> 2) * 16 + lhi * 4 + (i & 3);
        redbuf[w * 32 + fl] = nump[i];
      }
    }
    __syncthreads();
    if (tid < 32) {
      float s = 0.f;
#pragma unroll
      for (int j = 0; j < 8; ++j) s += redbuf[j * 32 + tid];
      anumS[tid] = s;
    }

    // ================= pass 2: sg -> den_res -> alpha_den =================
    float dacc[8];
#pragma unroll
    for (int i = 0; i < 8; ++i) dacc[i] = 0.f;
    for (int ch = 0; ch < 8; ++ch) {
      f32x4 sg[2][4];
#pragma unroll
      for (int mi = 0; mi < 2; ++mi)
#pragma unroll
        for (int ni = 0; ni < 4; ++ni)
          sg[mi][ni] = (f32x4){0.f, 0.f, 0.f, 0.f};
      {
        const f16* Bp = fT + (size_t)(ch * 512 + w * 64) * CDIM;
#pragma unroll
        for (int k = 0; k < 8; ++k) {
          const int ko = k * 32 + lhi * 8;
          f16x8 a0 = *(const f16x8*)&filt16[swz(llo, ko, 256)];       // = fgrad
          f16x8 a1 = *(const f16x8*)&filt16[swz(16 + llo, ko, 256)];
#pragma unroll
          for (int ni = 0; ni < 4; ++ni) {
            f16x8 bv = *(const f16x8*)&Bp[(ni * 16 + llo) * CDIM + ko];
            sg[0][ni] = __builtin_amdgcn_mfma_f32_16x16x32_f16(a0, bv, sg[0][ni], 0, 0, 0);
            sg[1][ni] = __builtin_amdgcn_mfma_f32_16x16x32_f16(a1, bv, sg[1][ni], 0, 0, 0);
          }
        }
      }
      {
        const unsigned int sbits = sgnB[(ch * 8 + w) * 64 + lane];
        const int iy = 63 - py + ch * 8 + w;
        const int tb = iy * 127 + 63 - pxb;
#pragma unroll
        for (int mi = 0; mi < 2; ++mi)
#pragma unroll
          for (int ni = 0; ni < 4; ++ni)
#pragma unroll
            for (int r = 0; r < 4; ++r) {
              const int fl = mi * 16 + lhi * 4 + r;
              const int x  = ni * 16 + llo;
              const float4 tv = tbl[tb - fl + x];
              const float q  = 0.5f * tv.y;
              const float qa = q * tv.z;
              const float h1 = q - qa, h2 = q + qa;
              const float sg0 = ((sbits >> (mi * 16 + ni * 4 + r)) & 1u) ? 1.f : -1.f;
              const float dct = h1 * sg0 + h2;
              const float dr  = dct * sg[mi][ni][r];
              dacc[mi * 4 + r] += dr * dr;
            }
      }
    }
#pragma unroll
    for (int i = 0; i < 8; ++i) {
      float v = dacc[i];
      v += __shfl_xor(v, 1); v += __shfl_xor(v, 2);
      v += __shfl_xor(v, 4); v += __shfl_xor(v, 8);
      dacc[i] = v;
    }
    __syncthreads();
    if (llo == 0) {
#pragma unroll
      for (int i = 0; i < 8; ++i) {
        const int fl = (i >> 2) * 16 + lhi * 4 + (i & 3);
        redbuf[w * 32 + fl] = dacc[i];
      }
    }
    __syncthreads();
    if (tid < 32) {
      float num = anumS[tid];
      float den = 0.f;
#pragma unroll
      for (int j = 0; j < 8; ++j) den += redbuf[j * 32 + tid];
      alphaS[tid] = num / fmaxf(den + rw * num, 1e-8f);  // STEPLEN_REG = 0
    }
    __syncthreads();
    // ================= update: filt -= sl*alpha*fgrad =================
#pragma unroll
    for (int mi = 0; mi < 2; ++mi)
#pragma unroll
      for (int nj = 0; nj < 2; ++nj)
#pragma unroll
        for (int r = 0; r < 4; ++r) {
          const int fl = mi * 16 + lhi * 4 + r;
          const int c  = w * 32 + nj * 16 + llo;
          const float nv = fm[mi][nj][r] - sl * alphaS[fl] * facc[mi][nj][r];
          fm[mi][nj][r] = nv;
          if (it == 0) filt16[swz(fl, c, 256)] = (f16)nv;
        }
    if (it == 0) __syncthreads();
  }

  // ================= output =================
  {
    float* og = out + ((size_t)b * NFILT + f0) * CDIM;
#pragma unroll
    for (int mi = 0; mi < 2; ++mi)
#pragma unroll
      for (int nj = 0; nj < 2; ++nj)
#pragma unroll
        for (int r = 0; r < 4; ++r) {
          const int fl = mi * 16 + lhi * 4 + r;
          const int c  = w * 32 + nj * 16 + llo;
          og[fl * CDIM + c] = fm[mi][nj][r];
        }
  }
}

extern "C" void kernel_launch(void* const* d_in, const int* in_sizes, int n_in,
                              void* d_out, int out_size, void* d_ws, size_t ws_size,
                              hipStream_t stream) {
  (void)in_sizes; (void)n_in; (void)out_size; (void)ws_size;
  const float* filt  = (const float*)d_in[0];   // filter_map [2][4096][256]
  const float* rfeat = (const float*)d_in[1];   // reference_feat [1][2][256][64][64]
  // d_in[2] query_feat: unused by the reference
  const float* wl  = (const float*)d_in[3];
  const float* wsp = (const float*)d_in[4];
  const float* wmk = (const float*)d_in[5];
  const float* lsl = (const float*)d_in[6];
  const float* fre = (const float*)d_in[7];

  char* ws = (char*)d_ws;
  float4* tbl = (float4*)(ws + 0);              // 127*127*16 B = 258064 (pad 256K)
  f16* featc  = (f16*)(ws + 262144);            // 4 MB
  f16* featT  = (f16*)(ws + 4456448);           // 4 MB
  unsigned int* sgn = (unsigned int*)(ws + 8650752);  // 4 MB
  float* out = (float*)d_out;

  k_maps<<<64, 256, 0, stream>>>(wl, wsp, wmk, tbl);
  k_convert<<<512, 256, 0, stream>>>(rfeat, featc, featT);
  k_gocor<<<256, 512, 0, stream>>>(filt, featc, featT, tbl, lsl, fre, sgn, out);
}